// Round 1
// baseline (280.517 us; speedup 1.0000x reference)
//
#include <hip/hip_runtime.h>
#include <math.h>

#define B     32
#define CIN   128
#define NN    8192
#define N1    8190     // output length after k=3 valid conv
#define CH    10
#define TOUT  252      // diag outputs per block (h2 tile = TOUT+4 = 256 cols, 1/thread)
#define NTILE 33       // ceil(8190/252)

// K0: transpose w1[o][ci][k] -> wT[ci][o*3+k] (rows padded to 32 floats)
// so k_main's per-channel 30 weights are contiguous wave-uniform s_loads.
__global__ void k0_prep(const float* __restrict__ w1, float* __restrict__ wT)
{
    const int i = blockIdx.x * 256 + threadIdx.x;     // 0..4095
    if (i < CIN * 32) {
        const int ci = i >> 5, r = i & 31;
        float v = 0.f;
        if (r < 30) {
            const int o = r / 3, k = r - o * 3;
            v = w1[(o * CIN + ci) * 3 + k];
        }
        wT[i] = v;
    }
}

// 8-channel FMA block: consumes one prefetched batch of 8 float4 rows.
__device__ __forceinline__ void chunk8(const float4 (&v)[8], int cbase,
                                       float (&y)[CH], bool sh,
                                       const float* __restrict__ wTl)
{
#pragma unroll
    for (int j = 0; j < 8; ++j) {
        const float s0 = sh ? v[j].y : v[j].x;        // signal[g]
        const float s1 = sh ? v[j].z : v[j].y;        // signal[g+1]
        const float s2 = sh ? v[j].w : v[j].z;        // signal[g+2]
        const float* wrow = wTl + (cbase + j) * 32;   // 30 contiguous uniform weights
#pragma unroll
        for (int o = 0; o < CH; ++o) {
            y[o] = fmaf(wrow[o * 3 + 0], s0, y[o]);
            y[o] = fmaf(wrow[o * 3 + 1], s1, y[o]);
            y[o] = fmaf(wrow[o * 3 + 2], s2, y[o]);
        }
    }
}

// K_MAIN: whole pipeline per 252-output tile.
// Phase 1: register double-buffered streaming conv1 — loads for chunk c+1
//   are issued BEFORE the FMAs of chunk c and pinned with sched_barrier(0)
//   so the compiler cannot serialize load->use (which is what capped the
//   previous version at 89us with VGPR=40 and VALUBusy=24%).
// Phase 2 (LDS): convT(k=3)+relu+1x1+sigmoid -> lr; tridiag+log; block sum.
__global__ __launch_bounds__(256, 4) void k_main(
    const float* __restrict__ sig, const float* __restrict__ wT,
    const float* __restrict__ b1, const float* __restrict__ w2, const float* __restrict__ b2,
    const float* __restrict__ wt, const float* __restrict__ bt,
    const float* __restrict__ w3, const float* __restrict__ b3,
    const float* __restrict__ cd, const float* __restrict__ cstp,
    float* __restrict__ outv, float* __restrict__ bsums)
{
    __shared__ float h2s[CH * 256];    // 10240 B  [o][col]
    __shared__ float lsh[256], rsh[256];
    __shared__ float red[4];

    const int tid = threadIdx.x;
    const int b   = blockIdx.y;
    const int t0  = blockIdx.x * TOUT;
    const int g   = t0 - 2 + tid;                     // h2 column of this thread
    const bool gvalid = (g >= 0) && (g < N1);
    const bool sh = (g > NN - 4);                     // only g==8189 among valid cols
    int gl = (g < 0) ? 0 : g;
    if (gl > NN - 4) gl = NN - 4;                     // float4 [gl..gl+3] always in-bounds
    const float* __restrict__ sb = sig + (size_t)b * CIN * NN + gl;

    float y[CH];
#pragma unroll
    for (int o = 0; o < CH; ++o) y[o] = b1[o];

    // ---- Phase 1: 16 chunks x 8 channels, double-buffered va/vb ----
    float4 va[8], vb[8];
#pragma unroll
    for (int j = 0; j < 8; ++j)
        va[j] = *(const float4*)(sb + (size_t)j * NN);         // chunk 0

    for (int c = 0; c < 16; c += 2) {                 // rolled: 8 iterations
        // prefetch chunk c+1
        const float* sc1 = sb + (size_t)(c + 1) * 8 * NN;
#pragma unroll
        for (int j = 0; j < 8; ++j)
            vb[j] = *(const float4*)(sc1 + (size_t)j * NN);
        __builtin_amdgcn_sched_barrier(0);            // loads stay ABOVE the FMAs
        chunk8(va, c * 8, y, sh, wT);

        // prefetch chunk c+2 (skip on last iteration)
        if (c < 14) {
            const float* sc2 = sb + (size_t)(c + 2) * 8 * NN;
#pragma unroll
            for (int j = 0; j < 8; ++j)
                va[j] = *(const float4*)(sc2 + (size_t)j * NN);
        }
        __builtin_amdgcn_sched_barrier(0);
        chunk8(vb, c * 8 + 8, y, sh, wT);
    }

    // conv2 (1x1) + relu -> LDS (zero outside [0,N1) for convT zero-padding)
#pragma unroll
    for (int o = 0; o < CH; ++o) y[o] = fmaxf(y[o], 0.f);
#pragma unroll
    for (int o = 0; o < CH; ++o) {
        float a = b2[o];
#pragma unroll
        for (int i = 0; i < CH; ++i) a = fmaf(w2[o * CH + i], y[i], a);
        h2s[o * 256 + tid] = gvalid ? fmaxf(a, 0.f) : 0.f;
    }
    __syncthreads();

    // convT + relu + 1x1 + sigmoid -> lr at s = t0 + tid (tid < 254)
    const int s = t0 + tid;
    if (tid < 254 && s < NN) {
        float acc[CH];
#pragma unroll
        for (int o = 0; o < CH; ++o) acc[o] = bt[o];
#pragma unroll
        for (int i = 0; i < CH; ++i) {
            const float a0 = h2s[i * 256 + tid];      // h2[s-2]
            const float a1 = h2s[i * 256 + tid + 1];  // h2[s-1]
            const float a2 = h2s[i * 256 + tid + 2];  // h2[s]
            const float* wp = wt + i * CH * 3;        // contiguous uniform
#pragma unroll
            for (int o = 0; o < CH; ++o) {
                acc[o] = fmaf(wp[o * 3 + 0], a2, acc[o]);
                acc[o] = fmaf(wp[o * 3 + 1], a1, acc[o]);
                acc[o] = fmaf(wp[o * 3 + 2], a0, acc[o]);
            }
        }
        float l = b3[0], r = b3[1];
#pragma unroll
        for (int o = 0; o < CH; ++o) {
            const float h3 = fmaxf(acc[o], 0.f);
            l = fmaf(w3[o],      h3, l);
            r = fmaf(w3[CH + o], h3, r);
        }
        lsh[tid] = 1.f / (1.f + __expf(-l));
        rsh[tid] = 1.f / (1.f + __expf(-r));
    }
    __syncthreads();

    // tridiagonal update + log for t = t0 + tid (tid < TOUT)
    float vlog = 0.f;
    const int t = t0 + tid;
    if (tid < TOUT && t < N1) {
        const float c0 = cd[(size_t)b * (NN - 1) + t];
        const float c1 = cd[(size_t)b * (NN - 1) + t + 1];
        const float mi = c1 * rsh[tid + 1] + c0 * lsh[tid + 1];
        const float mo = rsh[tid] + lsh[tid + 2];
        vlog = __logf(cstp[0] * mi / mo);
        outv[(size_t)b * N1 + t] = vlog;
    }

    // block sum: wave shuffle reduce, then 4 partials through LDS
    float vs = vlog;
#pragma unroll
    for (int off = 32; off > 0; off >>= 1) vs += __shfl_down(vs, off);
    if ((tid & 63) == 0) red[tid >> 6] = vs;
    __syncthreads();
    if (tid == 0)
        bsums[blockIdx.y * NTILE + blockIdx.x] = red[0] + red[1] + red[2] + red[3];
}

// K3: every block redundantly reduces the 1056 bsums (L2-hot), subtracts mean.
__global__ __launch_bounds__(256) void k3_meansub(
    const float* __restrict__ bsums, float* __restrict__ outv, int n)
{
    __shared__ float red[256];
    const int tid = threadIdx.x;
    float s = 0.f;
    for (int i = tid; i < NTILE * B; i += 256) s += bsums[i];
    red[tid] = s;
    __syncthreads();
#pragma unroll
    for (int st = 128; st > 0; st >>= 1) {
        if (tid < st) red[tid] += red[tid + st];
        __syncthreads();
    }
    const float mean = red[0] / (float)(B * N1);
    __syncthreads();
    const int i = blockIdx.x * 256 + tid;
    if (i < n) outv[i] -= mean;
}

extern "C" void kernel_launch(void* const* d_in, const int* in_sizes, int n_in,
                              void* d_out, int out_size, void* d_ws, size_t ws_size,
                              hipStream_t stream)
{
    const float* sig = (const float*)d_in[0];
    const float* cd  = (const float*)d_in[1];
    // d_in[2] = index_diag (1 for these shapes)
    const float* w1  = (const float*)d_in[3];
    const float* b1  = (const float*)d_in[4];
    const float* w2  = (const float*)d_in[5];
    const float* b2  = (const float*)d_in[6];
    const float* wt  = (const float*)d_in[7];
    const float* bt  = (const float*)d_in[8];
    const float* w3  = (const float*)d_in[9];
    const float* b3  = (const float*)d_in[10];
    const float* cst = (const float*)d_in[11];

    float* outv = (float*)d_out;

    // workspace layout (floats)
    float* ws   = (float*)d_ws;
    float* wT   = ws;                  // CIN*32 = 4096
    float* bsum = wT + CIN * 32;       // NTILE*B = 1056

    dim3 blk(256);

    k0_prep   <<<dim3(16), blk, 0, stream>>>(w1, wT);
    k_main    <<<dim3(NTILE, B), blk, 0, stream>>>(sig, wT, b1, w2, b2,
                                                   wt, bt, w3, b3, cd, cst, outv, bsum);
    k3_meansub<<<dim3((out_size + 255) / 256), blk, 0, stream>>>(bsum, outv, out_size);
}